// Round 6
// baseline (300.548 us; speedup 1.0000x reference)
//
#include <hip/hip_runtime.h>

#define NPOS 21824          // 16384+4096+1024+256+64 positions per image
#define MINS 0.05f
#define CAP  4096           // LDS candidate-list capacity

struct Ptrs { const float* cls[5]; const float* reg[5]; const float* ctr[5]; };

__device__ __forceinline__ float sigf(float x){ return 1.0f/(1.0f+expf(-x)); }

__device__ __forceinline__ unsigned long long mkkey(unsigned int bits, int p){
    return ((unsigned long long)bits << 16) | (unsigned)(65535 - p);
}

// exact reference box math: trunc-toward-zero then one-sided clamps
__device__ float4 decode_box(const Ptrs& P, int img, int p){
    int lvl, base, lw, stride;
    if (p < 16384)      { lvl=0; base=0;     lw=7; stride=8;   }
    else if (p < 20480) { lvl=1; base=16384; lw=6; stride=16;  }
    else if (p < 21504) { lvl=2; base=20480; lw=5; stride=32;  }
    else if (p < 21760) { lvl=3; base=21504; lw=4; stride=64;  }
    else                { lvl=4; base=21760; lw=3; stride=128; }
    int pl = p - base;
    int h = pl >> lw, w = pl & ((1<<lw)-1);
    long long lidx = (long long)img*(1<<(2*lw)) + pl;
    float4 rg = ((const float4*)P.reg[lvl])[lidx];
    float x = (w + 0.5f)*(float)stride;
    float y = (h + 0.5f)*(float)stride;
    int ix1 = (int)(x - expf(rg.x));
    int iy1 = (int)(y - expf(rg.y));
    int ix2 = (int)(x + expf(rg.z));
    int iy2 = (int)(y + expf(rg.w));
    ix1 = max(ix1,0); iy1 = max(iy1,0);
    ix2 = min(ix2,1023); iy2 = min(iy2,1023);
    return make_float4((float)ix1,(float)iy1,(float)ix2,(float)iy2);
}

// ------- Kernel A: score/class per position + per-image score histogram -----
// 4 lanes per position; level boundaries block-aligned (341 blocks * 64 pos).
__global__ __launch_bounds__(256) void k_score(Ptrs P, float* scoreAll, int* clsAll,
                                               unsigned int* ghist)
{
    int img  = blockIdx.y;
    int blk  = blockIdx.x;           // [0,341)
    int tid  = threadIdx.x;
    int posb = tid >> 2;
    int l    = tid & 3;
    int p    = blk*64 + posb;
    int lvl, base, lw;
    if (blk < 256)      { lvl=0; base=0;     lw=7; }
    else if (blk < 320) { lvl=1; base=16384; lw=6; }
    else if (blk < 336) { lvl=2; base=20480; lw=5; }
    else if (blk < 340) { lvl=3; base=21504; lw=4; }
    else                { lvl=4; base=21760; lw=3; }
    int pl = p - base;
    long long lidx = (long long)img*(1<<(2*lw)) + pl;

    const float4* c4 = (const float4*)(P.cls[lvl] + lidx*80);
    float mx = -3.4e38f; int mi = 0;
#pragma unroll
    for (int j = 0; j < 5; ++j) {
        int k = j*4 + l;
        float4 v = c4[k];
        int cb = k*4;
        if (v.x > mx){mx=v.x; mi=cb;}
        if (v.y > mx){mx=v.y; mi=cb+1;}
        if (v.z > mx){mx=v.z; mi=cb+2;}
        if (v.w > mx){mx=v.w; mi=cb+3;}
    }
#pragma unroll
    for (int d = 1; d < 4; d <<= 1) {
        float omx = __shfl_xor(mx, d);
        int   omi = __shfl_xor(mi, d);
        if (omx > mx || (omx == mx && omi < mi)) { mx = omx; mi = omi; }
    }
    if (l == 0) {
        float ct = P.ctr[lvl][lidx];
        float sc = sqrtf(sigf(mx)*sigf(ct));          // sigmoid(max)==max(sigmoid)
        int o = img*NPOS + p;
        scoreAll[o] = sc;
        clsAll[o]   = mi;
        atomicAdd(&ghist[img*4096 + (__float_as_uint(sc) >> 18)], 1u);
    }
}

// --- Kernel B: hist-guided top-256 + IoU-bitmatrix greedy NMS (8 blocks) ----
// key=(score_bits<<16)|(65535-p): desc key == desc score, ties lower p ==
// reference concat-order tie-break. Image top-256 by key == union top-256.
__global__ __launch_bounds__(256) void k_nms4(Ptrs P, const float* scoreAll,
                                              const int* clsAll,
                                              const unsigned int* ghist, float* out)
{
    __shared__ int hist[4096];
    __shared__ unsigned int lBits[CAP];
    __shared__ int lPos[CAP];
    __shared__ int wsum[4];
    __shared__ unsigned int shPref;
    __shared__ int shT, shAbove, tick, eqn, shNa, shFB, supFlag, cntR;
    __shared__ unsigned long long lastK;
    __shared__ int eq[256];
    __shared__ unsigned long long sel[256], sorted[256];
    __shared__ float4 sBox[256];
    __shared__ float  sCls[256], sA[256];
    __shared__ unsigned long long supMask[1024];   // 256 rows x 4 words; fallback: red[]
    __shared__ int    accList[100];
    __shared__ float4 accB[100];
    __shared__ float  accA[100];

    int img = blockIdx.x, tid = threadIdx.x;
    int lane = tid & 63, wv = tid >> 6;
    const unsigned int* gs = (const unsigned int*)scoreAll + (long long)img*NPOS;
    const int* gCls = clsAll + (long long)img*NPOS;

    // ---- phase 1: load 4096-bin histogram, suffix-scan for rank-256 bin T ----
    {
        const unsigned int* gh = ghist + img*4096;
        for (int i = tid; i < 4096; i += 256) hist[i] = (int)gh[i];
        __syncthreads();
        int lo = tid*16, ls = 0;
        for (int q = 0; q < 16; ++q) ls += hist[lo+q];
        int v = ls;
#pragma unroll
        for (int off = 1; off < 64; off <<= 1) {
            int o = __shfl_down(v, off);
            if (lane + off < 64) v += o;
        }
        if (lane == 0) wsum[wv] = v;
        __syncthreads();
        int add = 0;
        for (int q = wv + 1; q < 4; ++q) add += wsum[q];
        int mine  = v + add;             // suffix sum incl. own bins
        int above = mine - ls;           // suffix sum of higher threads
        if (above < 256 && mine >= 256) {   // exactly one thread crosses
            int cum = above;
            for (int b = lo + 15; b >= lo; --b) {
                cum += hist[b];
                if (cum >= 256) { shT = b; shAbove = cum - hist[b]; break; }
            }
        }
        __syncthreads();
    }
    int T = shT;
    int M = shAbove + hist[T];              // #scores with bin >= T (block-uniform)
    unsigned int thr = (unsigned int)T << 18;
    bool useL = (M <= CAP);

    // ---- phase 2: collect candidates with bin >= T into LDS list ----
    if (tid == 0) tick = 0;
    __syncthreads();
    if (useL) {
#pragma unroll 4
        for (int i = tid; i < NPOS; i += 256) {
            unsigned int b = gs[i];
            if (b >= thr) {
                int t = atomicAdd(&tick, 1);
                lBits[t] = b; lPos[t] = i;
            }
        }
    }
    __syncthreads();

    // ---- phase 3: exact 256th-largest score bits (18-bit count bit-search) ----
    if (tid == 0) shPref = thr;             // count(x >= thr) == M >= 256
    __syncthreads();
    for (int bit = 17; bit >= 0; --bit) {
        unsigned int t = shPref | (1u << bit);
        int c = 0;
        if (useL) { for (int i = tid; i < M;    i += 256) c += (lBits[i] >= t); }
        else      { for (int i = tid; i < NPOS; i += 256) c += (gs[i]    >= t); }
#pragma unroll
        for (int off = 1; off < 64; off <<= 1) c += __shfl_xor(c, off);
        if (lane == 0) wsum[wv] = c;
        __syncthreads();
        if (tid == 0 && (wsum[0]+wsum[1]+wsum[2]+wsum[3]) >= 256) shPref = t;
        __syncthreads();
    }
    unsigned int kth = shPref;              // largest v with count(x>=v) >= 256

    // ---- phase 4: build sel[256] (greater + lowest-p ties) ----
    if (tid == 0) { tick = 0; eqn = 0; }
    __syncthreads();
    if (useL) {
        for (int i = tid; i < M; i += 256) {
            unsigned int b = lBits[i];
            if (b > kth)       { int t = atomicAdd(&tick, 1); sel[t] = mkkey(b, lPos[i]); }
            else if (b == kth) { int t = atomicAdd(&eqn, 1); if (t < 256) eq[t] = lPos[i]; }
        }
    } else {
        for (int i = tid; i < NPOS; i += 256) {
            unsigned int b = gs[i];
            if (b > kth)       { int t = atomicAdd(&tick, 1); sel[t] = mkkey(b, i); }
            else if (b == kth) { int t = atomicAdd(&eqn, 1); if (t < 256) eq[t] = i; }
        }
    }
    __syncthreads();
    int m = eqn, nG = tick, need = 256 - nG;
    if (m <= 256) {                         // keep `need` lowest positions
        for (int q = tid; q < m; q += 256) {
            int pq = eq[q], r = 0;
            for (int j = 0; j < m; ++j) r += (eq[j] < pq);
            if (r < need) sel[nG + r] = mkkey(kth, pq);
        }
    } else if (tid == 0) {                  // unreachable-in-practice fallback
        int cnt = 0;
        for (int i = 0; i < NPOS && cnt < need; ++i)
            if (gs[i] == kth) { sel[nG + cnt] = mkkey(kth, i); ++cnt; }
    }
    __syncthreads();

    // ---- phase 5: rank-256 (unique keys), gather cls, decode boxes ----
    {
        unsigned long long k = sel[tid];
        int r = 0;
        for (int j = 0; j < 256; ++j) r += (sel[j] > k);
        sorted[r] = k;
    }
    __syncthreads();
    {
        int p = 65535 - (int)(sorted[tid] & 0xFFFF);
        float4 b = decode_box(P, img, p);
        sBox[tid] = b;
        sCls[tid] = (float)gCls[p];
        sA[tid]   = (b.z - b.x)*(b.w - b.y);
    }
    __syncthreads();

    // ---- phase 6: 256x256 suppression bitmatrix ----
    {
        float4 bt = sBox[tid]; float at = sA[tid];
        unsigned long long w0=0, w1=0, w2=0, w3=0;
        for (int j = 0; j < 256; ++j) {
            float4 bj = sBox[j];                       // broadcast LDS read
            float iw = fmaxf(fminf(bt.z,bj.z)-fmaxf(bt.x,bj.x),0.f);
            float ih = fmaxf(fminf(bt.w,bj.w)-fmaxf(bt.y,bj.y),0.f);
            float in_ = iw*ih;
            bool sup = (j != tid) && (in_/(at + sA[j] - in_ + 1e-12f) > 0.6f);
            unsigned long long bit = sup ? (1ull << (j & 63)) : 0ull;
            if (j < 64) w0 |= bit; else if (j < 128) w1 |= bit;
            else if (j < 192) w2 |= bit; else w3 |= bit;
        }
        supMask[tid*4+0]=w0; supMask[tid*4+1]=w1;
        supMask[tid*4+2]=w2; supMask[tid*4+3]=w3;
    }
    __syncthreads();

    // ---- phase 7: serial greedy scan (== sequential NMS) ----
    if (tid == 0) {
        unsigned long long a0=0, a1=0, a2=0, a3=0;
        int na = 0, fb = 1;
        for (int i = 0; i < 256; ++i) {
            float sc = __uint_as_float((unsigned int)(sorted[i] >> 16));
            if (!(sc > MINS)) { fb = 0; break; }
            bool sup = ((supMask[4*i]&a0)|(supMask[4*i+1]&a1)|
                        (supMask[4*i+2]&a2)|(supMask[4*i+3]&a3)) != 0ull;
            if (!sup) {
                if (i < 64) a0 |= 1ull<<i; else if (i < 128) a1 |= 1ull<<(i-64);
                else if (i < 192) a2 |= 1ull<<(i-128); else a3 |= 1ull<<(i-192);
                accList[na++] = i;
                if (na == 100) { fb = 0; break; }
            }
        }
        shNa = na; shFB = (fb && na < 100) ? 1 : 0; lastK = sorted[255];
    }
    __syncthreads();
    int na = shNa;
    float* outS = out + img*100;
    float* outC = out + 800 + img*100;
    float* outB = out + 1600 + img*400;
    if (tid < 100) {
        if (tid < na) {
            int ix = accList[tid];
            outS[tid] = __uint_as_float((unsigned int)(sorted[ix] >> 16));
            outC[tid] = sCls[ix];
            float4 b = sBox[ix];
            outB[4*tid]=b.x; outB[4*tid+1]=b.y; outB[4*tid+2]=b.z; outB[4*tid+3]=b.w;
            accB[tid] = b; accA[tid] = sA[ix];
        } else {
            outS[tid] = -1.f; outC[tid] = -1.f;
            outB[4*tid]=-1.f; outB[4*tid+1]=-1.f; outB[4*tid+2]=-1.f; outB[4*tid+3]=-1.f;
        }
    }
    __syncthreads();
    if (!shFB) return;

    // ---- exact slow fallback: top-256 exhausted (never on real data) ----
    unsigned long long* red = supMask;
    while (true) {
        unsigned long long lk = lastK, best = 0;
        for (int i = tid; i < NPOS; i += 256) {
            unsigned long long k = mkkey(gs[i], i);
            if (k < lk && k > best) best = k;
        }
        red[tid] = best;
        __syncthreads();
        if (tid == 0) {
            unsigned long long b = 0;
            for (int j = 0; j < 256; ++j) if (red[j] > b) b = red[j];
            red[0] = b;
        }
        __syncthreads();
        best = red[0];
        __syncthreads();
        if (best == 0ull) break;
        float sc = __uint_as_float((unsigned int)(best >> 16));
        if (!(sc > MINS)) break;
        int p = 65535 - (int)(best & 0xFFFF);
        int lvl = p < 16384 ? 0 : p < 20480 ? 1 : p < 21504 ? 2 : p < 21760 ? 3 : 4;
        bool elig = true;
        if (lvl < 3) {                      // union membership: level-rank < 1000
            int base = lvl == 0 ? 0 : (lvl == 1 ? 16384 : 20480);
            int Nl   = lvl == 0 ? 16384 : (lvl == 1 ? 4096 : 1024);
            if (tid == 0) cntR = 0;
            __syncthreads();
            int c = 0;
            for (int q = tid; q < Nl; q += 256)
                if (mkkey(gs[base+q], base+q) > best) ++c;
            atomicAdd(&cntR, c);
            __syncthreads();
            elig = (cntR < 1000);
        }
        if (elig) {
            float4 nb = decode_box(P, img, p);
            float nA = (nb.z - nb.x)*(nb.w - nb.y);
            if (tid == 0) supFlag = 0;
            __syncthreads();
            if (tid < shNa) {
                float4 ab = accB[tid];
                float iw = fmaxf(fminf(nb.z,ab.z)-fmaxf(nb.x,ab.x),0.f);
                float ih = fmaxf(fminf(nb.w,ab.w)-fmaxf(nb.y,ab.y),0.f);
                float in_ = iw*ih;
                if (in_/(nA + accA[tid] - in_ + 1e-12f) > 0.6f) atomicOr(&supFlag, 1);
            }
            __syncthreads();
            if (!supFlag) {
                if (tid == 0) {
                    int k2 = shNa;
                    outS[k2] = sc; outC[k2] = (float)gCls[p];
                    outB[4*k2]=nb.x; outB[4*k2+1]=nb.y; outB[4*k2+2]=nb.z; outB[4*k2+3]=nb.w;
                    accB[k2] = nb; accA[k2] = nA; shNa = k2 + 1;
                }
                __syncthreads();
                if (shNa >= 100) break;
            }
        }
        if (tid == 0) lastK = best;
        __syncthreads();
    }
}

extern "C" void kernel_launch(void* const* d_in, const int* in_sizes, int n_in,
                              void* d_out, int out_size, void* d_ws, size_t ws_size,
                              hipStream_t stream) {
    Ptrs P;
    bool interleaved = (in_sizes[1] == 8 * 128 * 128 * 4);
    for (int i = 0; i < 5; ++i) {
        if (interleaved) {
            P.cls[i] = (const float*)d_in[3*i];
            P.reg[i] = (const float*)d_in[3*i + 1];
            P.ctr[i] = (const float*)d_in[3*i + 2];
        } else {
            P.cls[i] = (const float*)d_in[i];
            P.reg[i] = (const float*)d_in[5 + i];
            P.ctr[i] = (const float*)d_in[10 + i];
        }
    }

    char* wbase = (char*)d_ws;
    size_t off = 0;
    auto alloc = [&](size_t bytes) -> void* {
        void* r = wbase + off;
        off += (bytes + 255) & ~(size_t)255;
        return r;
    };
    float*        scoreAll = (float*)alloc((size_t)8 * NPOS * 4);
    int*          clsAll   = (int*)alloc((size_t)8 * NPOS * 4);
    unsigned int* ghist    = (unsigned int*)alloc((size_t)8 * 4096 * 4);

    hipMemsetAsync(ghist, 0, (size_t)8 * 4096 * 4, stream);
    dim3 gA(341, 8);   // 341*64 = 21824 positions, level boundaries block-aligned
    k_score<<<gA, 256, 0, stream>>>(P, scoreAll, clsAll, ghist);
    k_nms4 <<<8, 256, 0, stream>>>(P, scoreAll, clsAll, ghist, (float*)d_out);
}

// Round 7
// 225.379 us; speedup vs baseline: 1.3335x; 1.3335x over previous
//
#include <hip/hip_runtime.h>

#define NPOS 21824          // 16384+4096+1024+256+64 positions per image
#define MINS 0.05f
#define CAP  4096           // global candidate-list capacity per image
#define STRIPE 682          // 21824 / 32

struct Ptrs { const float* cls[5]; const float* reg[5]; const float* ctr[5]; };

__device__ __forceinline__ float sigf(float x){ return 1.0f/(1.0f+expf(-x)); }

__device__ __forceinline__ unsigned long long mkkey(unsigned int bits, int p){
    return ((unsigned long long)bits << 16) | (unsigned)(65535 - p);
}

// exact reference box math: trunc-toward-zero then one-sided clamps
__device__ float4 decode_box(const Ptrs& P, int img, int p){
    int lvl, base, lw, stride;
    if (p < 16384)      { lvl=0; base=0;     lw=7; stride=8;   }
    else if (p < 20480) { lvl=1; base=16384; lw=6; stride=16;  }
    else if (p < 21504) { lvl=2; base=20480; lw=5; stride=32;  }
    else if (p < 21760) { lvl=3; base=21504; lw=4; stride=64;  }
    else                { lvl=4; base=21760; lw=3; stride=128; }
    int pl = p - base;
    int h = pl >> lw, w = pl & ((1<<lw)-1);
    long long lidx = (long long)img*(1<<(2*lw)) + pl;
    float4 rg = ((const float4*)P.reg[lvl])[lidx];
    float x = (w + 0.5f)*(float)stride;
    float y = (h + 0.5f)*(float)stride;
    int ix1 = (int)(x - expf(rg.x));
    int iy1 = (int)(y - expf(rg.y));
    int ix2 = (int)(x + expf(rg.z));
    int iy2 = (int)(y + expf(rg.w));
    ix1 = max(ix1,0); iy1 = max(iy1,0);
    ix2 = min(ix2,1023); iy2 = min(iy2,1023);
    return make_float4((float)ix1,(float)iy1,(float)ix2,(float)iy2);
}

// ------- Kernel A: score/class per position (no atomics, no box writes) -----
__global__ __launch_bounds__(256) void k_score(Ptrs P, float* scoreAll, int* clsAll)
{
    int img  = blockIdx.y;
    int blk  = blockIdx.x;           // [0,341)
    int tid  = threadIdx.x;
    int posb = tid >> 2;
    int l    = tid & 3;
    int p    = blk*64 + posb;
    int lvl, base, lw;
    if (blk < 256)      { lvl=0; base=0;     lw=7; }
    else if (blk < 320) { lvl=1; base=16384; lw=6; }
    else if (blk < 336) { lvl=2; base=20480; lw=5; }
    else if (blk < 340) { lvl=3; base=21504; lw=4; }
    else                { lvl=4; base=21760; lw=3; }
    int pl = p - base;
    long long lidx = (long long)img*(1<<(2*lw)) + pl;

    const float4* c4 = (const float4*)(P.cls[lvl] + lidx*80);
    float mx = -3.4e38f; int mi = 0;
#pragma unroll
    for (int j = 0; j < 5; ++j) {
        int k = j*4 + l;
        float4 v = c4[k];
        int cb = k*4;
        if (v.x > mx){mx=v.x; mi=cb;}
        if (v.y > mx){mx=v.y; mi=cb+1;}
        if (v.z > mx){mx=v.z; mi=cb+2;}
        if (v.w > mx){mx=v.w; mi=cb+3;}
    }
#pragma unroll
    for (int d = 1; d < 4; d <<= 1) {
        float omx = __shfl_xor(mx, d);
        int   omi = __shfl_xor(mi, d);
        if (omx > mx || (omx == mx && omi < mi)) { mx = omx; mi = omi; }
    }
    if (l == 0) {
        float ct = P.ctr[lvl][lidx];
        float sc = sqrtf(sigf(mx)*sigf(ct));          // sigmoid(max)==max(sigmoid)
        int o = img*NPOS + p;
        scoreAll[o] = sc;
        clsAll[o]   = mi;
    }
}

// ------- Kernel B: per-stripe LDS histogram -> merge nonzero bins -----------
// 256 blocks: img = bid>>5, stripe = bid&31 (682 positions each).
__global__ __launch_bounds__(256) void k_hist(const float* scoreAll,
                                              unsigned int* ghist)
{
    __shared__ int hist[4096];
    int bid = blockIdx.x, tid = threadIdx.x;
    int img = bid >> 5, stripe = bid & 31;
    const unsigned int* gs = (const unsigned int*)scoreAll
                             + (long long)img*NPOS + stripe*STRIPE;
    for (int i = tid; i < 4096; i += 256) hist[i] = 0;
    __syncthreads();
    for (int i = tid; i < STRIPE; i += 256)
        atomicAdd(&hist[gs[i] >> 18], 1);             // score<=1 -> bin<4096
    __syncthreads();
    unsigned int* gh = ghist + img*4096;
    for (int i = tid; i < 4096; i += 256)
        if (hist[i]) atomicAdd(&gh[i], (unsigned int)hist[i]);
}

// ------- Kernel C: T from histogram + stripe scan + aggregated append -------
__global__ __launch_bounds__(256) void k_collect(const float* scoreAll,
                                                 const unsigned int* ghist,
                                                 unsigned long long* gList,
                                                 int* gtick)
{
    __shared__ int hist[4096];
    __shared__ int wsum[4];
    __shared__ int shT, lt, gbase;
    __shared__ unsigned long long loc[704];
    int bid = blockIdx.x, tid = threadIdx.x;
    int img = bid >> 5, stripe = bid & 31;
    int lane = tid & 63, wv = tid >> 6;
    const unsigned int* gh = ghist + img*4096;
    for (int i = tid; i < 4096; i += 256) hist[i] = (int)gh[i];
    if (tid == 0) lt = 0;
    __syncthreads();

    // suffix-scan for rank-256 bin T (validated round-6 structure)
    {
        int lo = tid*16, ls = 0;
        for (int q = 0; q < 16; ++q) ls += hist[lo+q];
        int v = ls;
#pragma unroll
        for (int off = 1; off < 64; off <<= 1) {
            int o = __shfl_down(v, off);
            if (lane + off < 64) v += o;
        }
        if (lane == 0) wsum[wv] = v;
        __syncthreads();
        int add = 0;
        for (int q = wv + 1; q < 4; ++q) add += wsum[q];
        int mine  = v + add;
        int above = mine - ls;
        if (above < 256 && mine >= 256) {             // exactly one thread
            int cum = above;
            for (int b = lo + 15; b >= lo; --b) {
                cum += hist[b];
                if (cum >= 256) { shT = b; break; }
            }
        }
        __syncthreads();
    }
    unsigned int thr = (unsigned int)shT << 18;

    const unsigned int* gs = (const unsigned int*)scoreAll
                             + (long long)img*NPOS + stripe*STRIPE;
    for (int i = tid; i < STRIPE; i += 256) {
        unsigned int b = gs[i];
        if (b >= thr) {
            int t = atomicAdd(&lt, 1);
            loc[t] = mkkey(b, stripe*STRIPE + i);
        }
    }
    __syncthreads();
    if (tid == 0) gbase = atomicAdd(&gtick[img], lt); // one global atomic/block
    __syncthreads();
    int n = lt, gb = gbase;
    for (int i = tid; i < n; i += 256) {
        int g = gb + i;
        if (g < CAP) gList[(long long)img*CAP + g] = loc[i];
    }
}

// ------- Kernel D: exact top-256 from list + IoU-bitmatrix greedy NMS -------
// key=(score_bits<<16)|(65535-p): desc key == desc score, ties lower p ==
// reference concat-order tie-break. Image top-256 == union top-256.
__global__ __launch_bounds__(256) void k_nms5(Ptrs P, const float* scoreAll,
                                              const int* clsAll,
                                              const unsigned long long* gList,
                                              const int* gtick, float* out)
{
    __shared__ unsigned long long lKey[CAP];
    __shared__ int wsum[4];
    __shared__ unsigned int shPref;
    __shared__ int tick, eqn, shNa, shFB, supFlag, cntR;
    __shared__ unsigned long long lastK;
    __shared__ int eq[256];
    __shared__ unsigned long long sel[256], sorted[256];
    __shared__ float4 sBox[256];
    __shared__ float  sCls[256], sA[256];
    __shared__ unsigned long long supMask[1024];      // 256 rows x 4; fallback: red[]
    __shared__ int    accList[100];
    __shared__ float4 accB[100];
    __shared__ float  accA[100];

    int img = blockIdx.x, tid = threadIdx.x;
    int lane = tid & 63, wv = tid >> 6;
    const unsigned int* gs = (const unsigned int*)scoreAll + (long long)img*NPOS;
    const int* gCls = clsAll + (long long)img*NPOS;

    int M = gtick[img];
    bool useL = (M <= CAP);
    if (useL)
        for (int i = tid; i < M; i += 256)
            lKey[i] = gList[(long long)img*CAP + i];
    __syncthreads();

    // ---- exact 256th-largest score bits: 32-step count bit-search ----
    // Predicate over list == predicate over image: for t<=thr both counts>=256;
    // for t>thr the list contains every score >= t.
    if (tid == 0) shPref = 0;
    __syncthreads();
    for (int bit = 31; bit >= 0; --bit) {
        unsigned int t = shPref | (1u << bit);
        int c = 0;
        if (useL) { for (int i = tid; i < M;    i += 256) c += ((unsigned int)(lKey[i] >> 16) >= t); }
        else      { for (int i = tid; i < NPOS; i += 256) c += (gs[i] >= t); }
#pragma unroll
        for (int off = 1; off < 64; off <<= 1) c += __shfl_xor(c, off);
        if (lane == 0) wsum[wv] = c;
        __syncthreads();
        if (tid == 0 && (wsum[0]+wsum[1]+wsum[2]+wsum[3]) >= 256) shPref = t;
        __syncthreads();
    }
    unsigned int kth = shPref;             // largest v with count(x>=v) >= 256

    // ---- build sel[256]: all greater + lowest-p ties ----
    if (tid == 0) { tick = 0; eqn = 0; }
    __syncthreads();
    if (useL) {
        for (int i = tid; i < M; i += 256) {
            unsigned long long k = lKey[i];
            unsigned int b = (unsigned int)(k >> 16);
            if (b > kth)       { int t = atomicAdd(&tick, 1); sel[t] = k; }
            else if (b == kth) { int t = atomicAdd(&eqn, 1);
                                 if (t < 256) eq[t] = 65535 - (int)(k & 0xFFFF); }
        }
    } else {
        for (int i = tid; i < NPOS; i += 256) {
            unsigned int b = gs[i];
            if (b > kth)       { int t = atomicAdd(&tick, 1); sel[t] = mkkey(b, i); }
            else if (b == kth) { int t = atomicAdd(&eqn, 1); if (t < 256) eq[t] = i; }
        }
    }
    __syncthreads();
    int m = eqn, nG = tick, need = 256 - nG;
    if (m <= 256) {                        // keep `need` lowest positions
        for (int q = tid; q < m; q += 256) {
            int pq = eq[q], r = 0;
            for (int j = 0; j < m; ++j) r += (eq[j] < pq);
            if (r < need) sel[nG + r] = mkkey(kth, pq);
        }
    } else if (tid == 0) {                 // unreachable-in-practice fallback
        int cnt = 0;
        for (int i = 0; i < NPOS && cnt < need; ++i)
            if (gs[i] == kth) { sel[nG + cnt] = mkkey(kth, i); ++cnt; }
    }
    __syncthreads();

    // ---- rank-256 (unique keys), gather cls, decode boxes ----
    {
        unsigned long long k = sel[tid];
        int r = 0;
        for (int j = 0; j < 256; ++j) r += (sel[j] > k);
        sorted[r] = k;
    }
    __syncthreads();
    {
        int p = 65535 - (int)(sorted[tid] & 0xFFFF);
        float4 b = decode_box(P, img, p);
        sBox[tid] = b;
        sCls[tid] = (float)gCls[p];
        sA[tid]   = (b.z - b.x)*(b.w - b.y);
    }
    __syncthreads();

    // ---- 256x256 suppression bitmatrix ----
    {
        float4 bt = sBox[tid]; float at = sA[tid];
        unsigned long long w0=0, w1=0, w2=0, w3=0;
        for (int j = 0; j < 256; ++j) {
            float4 bj = sBox[j];                       // broadcast LDS read
            float iw = fmaxf(fminf(bt.z,bj.z)-fmaxf(bt.x,bj.x),0.f);
            float ih = fmaxf(fminf(bt.w,bj.w)-fmaxf(bt.y,bj.y),0.f);
            float in_ = iw*ih;
            bool sup = (j != tid) && (in_/(at + sA[j] - in_ + 1e-12f) > 0.6f);
            unsigned long long bit = sup ? (1ull << (j & 63)) : 0ull;
            if (j < 64) w0 |= bit; else if (j < 128) w1 |= bit;
            else if (j < 192) w2 |= bit; else w3 |= bit;
        }
        supMask[tid*4+0]=w0; supMask[tid*4+1]=w1;
        supMask[tid*4+2]=w2; supMask[tid*4+3]=w3;
    }
    __syncthreads();

    // ---- serial greedy scan: 4-word AND per candidate (== sequential NMS) ----
    if (tid == 0) {
        unsigned long long a0=0, a1=0, a2=0, a3=0;
        int na = 0, fb = 1;
        for (int i = 0; i < 256; ++i) {
            float sc = __uint_as_float((unsigned int)(sorted[i] >> 16));
            if (!(sc > MINS)) { fb = 0; break; }
            bool sup = ((supMask[4*i]&a0)|(supMask[4*i+1]&a1)|
                        (supMask[4*i+2]&a2)|(supMask[4*i+3]&a3)) != 0ull;
            if (!sup) {
                if (i < 64) a0 |= 1ull<<i; else if (i < 128) a1 |= 1ull<<(i-64);
                else if (i < 192) a2 |= 1ull<<(i-128); else a3 |= 1ull<<(i-192);
                accList[na++] = i;
                if (na == 100) { fb = 0; break; }
            }
        }
        shNa = na; shFB = (fb && na < 100) ? 1 : 0; lastK = sorted[255];
    }
    __syncthreads();
    int na = shNa;
    float* outS = out + img*100;
    float* outC = out + 800 + img*100;
    float* outB = out + 1600 + img*400;
    if (tid < 100) {
        if (tid < na) {
            int ix = accList[tid];
            outS[tid] = __uint_as_float((unsigned int)(sorted[ix] >> 16));
            outC[tid] = sCls[ix];
            float4 b = sBox[ix];
            outB[4*tid]=b.x; outB[4*tid+1]=b.y; outB[4*tid+2]=b.z; outB[4*tid+3]=b.w;
            accB[tid] = b; accA[tid] = sA[ix];
        } else {
            outS[tid] = -1.f; outC[tid] = -1.f;
            outB[4*tid]=-1.f; outB[4*tid+1]=-1.f; outB[4*tid+2]=-1.f; outB[4*tid+3]=-1.f;
        }
    }
    __syncthreads();
    if (!shFB) return;

    // ---- exact slow fallback: top-256 exhausted (never on real data) ----
    unsigned long long* red = supMask;
    while (true) {
        unsigned long long lk = lastK, best = 0;
        for (int i = tid; i < NPOS; i += 256) {
            unsigned long long k = mkkey(gs[i], i);
            if (k < lk && k > best) best = k;
        }
        red[tid] = best;
        __syncthreads();
        if (tid == 0) {
            unsigned long long b = 0;
            for (int j = 0; j < 256; ++j) if (red[j] > b) b = red[j];
            red[0] = b;
        }
        __syncthreads();
        best = red[0];
        __syncthreads();
        if (best == 0ull) break;
        float sc = __uint_as_float((unsigned int)(best >> 16));
        if (!(sc > MINS)) break;
        int p = 65535 - (int)(best & 0xFFFF);
        int lvl = p < 16384 ? 0 : p < 20480 ? 1 : p < 21504 ? 2 : p < 21760 ? 3 : 4;
        bool elig = true;
        if (lvl < 3) {                     // union membership: level-rank < 1000
            int base = lvl == 0 ? 0 : (lvl == 1 ? 16384 : 20480);
            int Nl   = lvl == 0 ? 16384 : (lvl == 1 ? 4096 : 1024);
            if (tid == 0) cntR = 0;
            __syncthreads();
            int c = 0;
            for (int q = tid; q < Nl; q += 256)
                if (mkkey(gs[base+q], base+q) > best) ++c;
            atomicAdd(&cntR, c);
            __syncthreads();
            elig = (cntR < 1000);
        }
        if (elig) {
            float4 nb = decode_box(P, img, p);
            float nA = (nb.z - nb.x)*(nb.w - nb.y);
            if (tid == 0) supFlag = 0;
            __syncthreads();
            if (tid < shNa) {
                float4 ab = accB[tid];
                float iw = fmaxf(fminf(nb.z,ab.z)-fmaxf(nb.x,ab.x),0.f);
                float ih = fmaxf(fminf(nb.w,ab.w)-fmaxf(nb.y,ab.y),0.f);
                float in_ = iw*ih;
                if (in_/(nA + accA[tid] - in_ + 1e-12f) > 0.6f) atomicOr(&supFlag, 1);
            }
            __syncthreads();
            if (!supFlag) {
                if (tid == 0) {
                    int k2 = shNa;
                    outS[k2] = sc; outC[k2] = (float)gCls[p];
                    outB[4*k2]=nb.x; outB[4*k2+1]=nb.y; outB[4*k2+2]=nb.z; outB[4*k2+3]=nb.w;
                    accB[k2] = nb; accA[k2] = nA; shNa = k2 + 1;
                }
                __syncthreads();
                if (shNa >= 100) break;
            }
        }
        if (tid == 0) lastK = best;
        __syncthreads();
    }
}

extern "C" void kernel_launch(void* const* d_in, const int* in_sizes, int n_in,
                              void* d_out, int out_size, void* d_ws, size_t ws_size,
                              hipStream_t stream) {
    Ptrs P;
    bool interleaved = (in_sizes[1] == 8 * 128 * 128 * 4);
    for (int i = 0; i < 5; ++i) {
        if (interleaved) {
            P.cls[i] = (const float*)d_in[3*i];
            P.reg[i] = (const float*)d_in[3*i + 1];
            P.ctr[i] = (const float*)d_in[3*i + 2];
        } else {
            P.cls[i] = (const float*)d_in[i];
            P.reg[i] = (const float*)d_in[5 + i];
            P.ctr[i] = (const float*)d_in[10 + i];
        }
    }

    char* wbase = (char*)d_ws;
    size_t off = 0;
    auto alloc = [&](size_t bytes) -> void* {
        void* r = wbase + off;
        off += (bytes + 255) & ~(size_t)255;
        return r;
    };
    float*              scoreAll = (float*)alloc((size_t)8 * NPOS * 4);
    int*                clsAll   = (int*)alloc((size_t)8 * NPOS * 4);
    unsigned int*       ghist    = (unsigned int*)alloc((size_t)8 * 4096 * 4);
    int*                gtick    = (int*)alloc(256);              // adjacent to ghist
    unsigned long long* gList    = (unsigned long long*)alloc((size_t)8 * CAP * 8);

    // one memset covers ghist (128 KB, 256-aligned) + gtick (256 B)
    hipMemsetAsync(ghist, 0, (size_t)8 * 4096 * 4 + 256, stream);

    dim3 gA(341, 8);   // 341*64 = 21824 positions, level boundaries block-aligned
    k_score  <<<gA,  256, 0, stream>>>(P, scoreAll, clsAll);
    k_hist   <<<256, 256, 0, stream>>>(scoreAll, ghist);
    k_collect<<<256, 256, 0, stream>>>(scoreAll, ghist, gList, gtick);
    k_nms5   <<<8,   256, 0, stream>>>(P, scoreAll, clsAll, gList, gtick,
                                       (float*)d_out);
}

// Round 8
// 222.155 us; speedup vs baseline: 1.3529x; 1.0145x over previous
//
#include <hip/hip_runtime.h>

#define NPOS 21824          // 16384+4096+1024+256+64 positions per image
#define MINS 0.05f
#define CAP  4096           // LDS candidate-list capacity

struct Ptrs { const float* cls[5]; const float* reg[5]; const float* ctr[5]; };

__device__ __forceinline__ float sigf(float x){ return 1.0f/(1.0f+expf(-x)); }

__device__ __forceinline__ unsigned long long mkkey(unsigned int bits, int p){
    return ((unsigned long long)bits << 16) | (unsigned)(65535 - p);
}

// exact reference box math: trunc-toward-zero then one-sided clamps
__device__ float4 decode_box(const Ptrs& P, int img, int p){
    int lvl, base, lw, stride;
    if (p < 16384)      { lvl=0; base=0;     lw=7; stride=8;   }
    else if (p < 20480) { lvl=1; base=16384; lw=6; stride=16;  }
    else if (p < 21504) { lvl=2; base=20480; lw=5; stride=32;  }
    else if (p < 21760) { lvl=3; base=21504; lw=4; stride=64;  }
    else                { lvl=4; base=21760; lw=3; stride=128; }
    int pl = p - base;
    int h = pl >> lw, w = pl & ((1<<lw)-1);
    long long lidx = (long long)img*(1<<(2*lw)) + pl;
    float4 rg = ((const float4*)P.reg[lvl])[lidx];
    float x = (w + 0.5f)*(float)stride;
    float y = (h + 0.5f)*(float)stride;
    int ix1 = (int)(x - expf(rg.x));
    int iy1 = (int)(y - expf(rg.y));
    int ix2 = (int)(x + expf(rg.z));
    int iy2 = (int)(y + expf(rg.w));
    ix1 = max(ix1,0); iy1 = max(iy1,0);
    ix2 = min(ix2,1023); iy2 = min(iy2,1023);
    return make_float4((float)ix1,(float)iy1,(float)ix2,(float)iy2);
}

// ------- Kernel A: score/class per position (validated round-7 code) --------
__global__ __launch_bounds__(256) void k_score(Ptrs P, float* scoreAll, int* clsAll)
{
    int img  = blockIdx.y;
    int blk  = blockIdx.x;           // [0,341)
    int tid  = threadIdx.x;
    int posb = tid >> 2;
    int l    = tid & 3;
    int p    = blk*64 + posb;
    int lvl, base, lw;
    if (blk < 256)      { lvl=0; base=0;     lw=7; }
    else if (blk < 320) { lvl=1; base=16384; lw=6; }
    else if (blk < 336) { lvl=2; base=20480; lw=5; }
    else if (blk < 340) { lvl=3; base=21504; lw=4; }
    else                { lvl=4; base=21760; lw=3; }
    int pl = p - base;
    long long lidx = (long long)img*(1<<(2*lw)) + pl;

    const float4* c4 = (const float4*)(P.cls[lvl] + lidx*80);
    float mx = -3.4e38f; int mi = 0;
#pragma unroll
    for (int j = 0; j < 5; ++j) {
        int k = j*4 + l;
        float4 v = c4[k];
        int cb = k*4;
        if (v.x > mx){mx=v.x; mi=cb;}
        if (v.y > mx){mx=v.y; mi=cb+1;}
        if (v.z > mx){mx=v.z; mi=cb+2;}
        if (v.w > mx){mx=v.w; mi=cb+3;}
    }
#pragma unroll
    for (int d = 1; d < 4; d <<= 1) {
        float omx = __shfl_xor(mx, d);
        int   omi = __shfl_xor(mi, d);
        if (omx > mx || (omx == mx && omi < mi)) { mx = omx; mi = omi; }
    }
    if (l == 0) {
        float ct = P.ctr[lvl][lidx];
        float sc = sqrtf(sigf(mx)*sigf(ct));          // sigmoid(max)==max(sigmoid)
        int o = img*NPOS + p;
        scoreAll[o] = sc;
        clsAll[o]   = mi;
    }
}

// ---- Kernel B: fully-fused per-image top-256 + IoU-bitmatrix NMS (8 blks) --
// key=(score_bits<<16)|(65535-p): desc key == desc score, ties lower p ==
// reference concat-order tie-break. Image top-256 by key == union top-256.
__global__ __launch_bounds__(256) void k_nms6(Ptrs P, const float* scoreAll,
                                              const int* clsAll, float* out)
{
    __shared__ __align__(16) unsigned char smem[65536];
    int* hist = (int*)smem;                                         // [16384] ph1-2
    unsigned long long* lKey = (unsigned long long*)smem;           // [4096]  ph3+
    unsigned long long* sorted = (unsigned long long*)(smem+32768); // [256]
    float4* sBox = (float4*)(smem+34816);                           // [256]
    float*  sCls = (float*)(smem+38912);                            // [256]
    float*  sA   = (float*)(smem+39936);                            // [256]
    unsigned long long* supMask = (unsigned long long*)(smem+40960);// [1024] / red
    int* eq = (int*)(smem+49152);                                   // [256] fallback
    unsigned long long* selA = (unsigned long long*)(smem+50176);   // [256] fallback

    __shared__ int wsum[4];
    __shared__ unsigned int shPref;
    __shared__ int shT, tick, eqn, shNa, shFB, supFlag, cntR;
    __shared__ unsigned long long lastK;
    __shared__ int    accList[100];
    __shared__ float4 accB[100];
    __shared__ float  accA[100];

    int img = blockIdx.x, tid = threadIdx.x;
    int lane = tid & 63, wv = tid >> 6;
    const unsigned int* gs = (const unsigned int*)scoreAll + (long long)img*NPOS;
    const uint4* gs4 = (const uint4*)gs;                 // NPOS % 4 == 0
    const int* gCls = clsAll + (long long)img*NPOS;

    // ---- phase 1: 16384-bin LDS histogram of score bits >> 16 ----
    {
        int4* h4 = (int4*)hist;
        for (int i = tid; i < 4096; i += 256) h4[i] = make_int4(0,0,0,0);
    }
    __syncthreads();
    for (int i = tid; i < NPOS/4; i += 256) {
        uint4 v = gs4[i];
        atomicAdd(&hist[v.x >> 16], 1);
        atomicAdd(&hist[v.y >> 16], 1);
        atomicAdd(&hist[v.z >> 16], 1);
        atomicAdd(&hist[v.w >> 16], 1);
    }
    __syncthreads();

    // ---- phase 2: suffix-scan for rank-256 bin T ----
    {
        int lo = tid*64, ls = 0;
        for (int q = 0; q < 64; ++q) ls += hist[lo+q];
        int v = ls;
#pragma unroll
        for (int off = 1; off < 64; off <<= 1) {
            int o = __shfl_down(v, off);
            if (lane + off < 64) v += o;
        }
        if (lane == 0) wsum[wv] = v;
        __syncthreads();
        int add = 0;
        for (int q = wv + 1; q < 4; ++q) add += wsum[q];
        int mine  = v + add;             // suffix incl. own bins
        int above = mine - ls;           // suffix of higher threads
        if (above < 256 && mine >= 256) {            // exactly one thread
            int cum = above;
            for (int b = lo + 63; b >= lo; --b) {
                cum += hist[b];
                if (cum >= 256) { shT = b; break; }
            }
        }
        if (tid == 0) tick = 0;
        __syncthreads();                 // hist dead after this barrier
    }
    unsigned int thr = (unsigned int)shT << 16;

    // ---- phase 3: collect keys with bits >= thr into LDS list ----
    for (int i = tid; i < NPOS/4; i += 256) {
        uint4 v = gs4[i];
        int p4 = 4*i;
        if (v.x >= thr) { int t = atomicAdd(&tick,1); if (t<CAP) lKey[t]=mkkey(v.x,p4  ); }
        if (v.y >= thr) { int t = atomicAdd(&tick,1); if (t<CAP) lKey[t]=mkkey(v.y,p4+1); }
        if (v.z >= thr) { int t = atomicAdd(&tick,1); if (t<CAP) lKey[t]=mkkey(v.z,p4+2); }
        if (v.w >= thr) { int t = atomicAdd(&tick,1); if (t<CAP) lKey[t]=mkkey(v.w,p4+3); }
    }
    __syncthreads();
    int M = tick;                        // M >= 256 by construction of T
    bool useL = (M <= CAP);

    if (useL) {
        // ---- phase 4a: rank-by-counting -> sorted[0..255] (keys unique) ----
        int nk = (M + 255) >> 8;
        for (int q = 0; q < nk; ++q) {
            int idx = tid + q*256;
            if (idx < M) {
                unsigned long long k = lKey[idx];
                int r = 0;
                for (int j = 0; j < M; ++j) r += (lKey[j] > k);  // broadcast reads
                if (r < 256) sorted[r] = k;
            }
        }
        __syncthreads();
    } else {
        // ---- phase 4b: exact fallback — 32-step bit-search over global ----
        if (tid == 0) shPref = 0;
        __syncthreads();
        for (int bit = 31; bit >= 0; --bit) {
            unsigned int t = shPref | (1u << bit);
            int c = 0;
            for (int i = tid; i < NPOS; i += 256) c += (gs[i] >= t);
#pragma unroll
            for (int off = 1; off < 64; off <<= 1) c += __shfl_xor(c, off);
            if (lane == 0) wsum[wv] = c;
            __syncthreads();
            if (tid == 0 && (wsum[0]+wsum[1]+wsum[2]+wsum[3]) >= 256) shPref = t;
            __syncthreads();
        }
        unsigned int kth = shPref;
        if (tid == 0) { tick = 0; eqn = 0; }
        __syncthreads();
        for (int i = tid; i < NPOS; i += 256) {
            unsigned int b = gs[i];
            if (b > kth)       { int t = atomicAdd(&tick, 1); selA[t] = mkkey(b, i); }
            else if (b == kth) { int t = atomicAdd(&eqn, 1); if (t < 256) eq[t] = i; }
        }
        __syncthreads();
        int m = eqn, nG = tick, need = 256 - nG;
        if (m <= 256) {
            for (int q = tid; q < m; q += 256) {
                int pq = eq[q], r = 0;
                for (int j = 0; j < m; ++j) r += (eq[j] < pq);
                if (r < need) selA[nG + r] = mkkey(kth, pq);
            }
        } else if (tid == 0) {
            int cnt = 0;
            for (int i = 0; i < NPOS && cnt < need; ++i)
                if (gs[i] == kth) { selA[nG + cnt] = mkkey(kth, i); ++cnt; }
        }
        __syncthreads();
        {
            unsigned long long k = selA[tid];
            int r = 0;
            for (int j = 0; j < 256; ++j) r += (selA[j] > k);
            sorted[r] = k;
        }
        __syncthreads();
    }

    // ---- phase 5: gather cls, decode boxes for the 256 ----
    {
        int p = 65535 - (int)(sorted[tid] & 0xFFFF);
        float4 b = decode_box(P, img, p);
        sBox[tid] = b;
        sCls[tid] = (float)gCls[p];
        sA[tid]   = (b.z - b.x)*(b.w - b.y);
    }
    __syncthreads();

    // ---- phase 6: 256x256 suppression bitmatrix ----
    {
        float4 bt = sBox[tid]; float at = sA[tid];
        unsigned long long w0=0, w1=0, w2=0, w3=0;
        for (int j = 0; j < 256; ++j) {
            float4 bj = sBox[j];                       // broadcast LDS read
            float iw = fmaxf(fminf(bt.z,bj.z)-fmaxf(bt.x,bj.x),0.f);
            float ih = fmaxf(fminf(bt.w,bj.w)-fmaxf(bt.y,bj.y),0.f);
            float in_ = iw*ih;
            bool sup = (j != tid) && (in_/(at + sA[j] - in_ + 1e-12f) > 0.6f);
            unsigned long long bit = sup ? (1ull << (j & 63)) : 0ull;
            if (j < 64) w0 |= bit; else if (j < 128) w1 |= bit;
            else if (j < 192) w2 |= bit; else w3 |= bit;
        }
        supMask[tid*4+0]=w0; supMask[tid*4+1]=w1;
        supMask[tid*4+2]=w2; supMask[tid*4+3]=w3;
    }
    __syncthreads();

    // ---- phase 7: serial greedy scan (== sequential NMS) ----
    if (tid == 0) {
        unsigned long long a0=0, a1=0, a2=0, a3=0;
        int na = 0, fb = 1;
        for (int i = 0; i < 256; ++i) {
            float sc = __uint_as_float((unsigned int)(sorted[i] >> 16));
            if (!(sc > MINS)) { fb = 0; break; }
            bool sup = ((supMask[4*i]&a0)|(supMask[4*i+1]&a1)|
                        (supMask[4*i+2]&a2)|(supMask[4*i+3]&a3)) != 0ull;
            if (!sup) {
                if (i < 64) a0 |= 1ull<<i; else if (i < 128) a1 |= 1ull<<(i-64);
                else if (i < 192) a2 |= 1ull<<(i-128); else a3 |= 1ull<<(i-192);
                accList[na++] = i;
                if (na == 100) { fb = 0; break; }
            }
        }
        shNa = na; shFB = (fb && na < 100) ? 1 : 0; lastK = sorted[255];
    }
    __syncthreads();
    int na = shNa;
    float* outS = out + img*100;
    float* outC = out + 800 + img*100;
    float* outB = out + 1600 + img*400;
    if (tid < 100) {
        if (tid < na) {
            int ix = accList[tid];
            outS[tid] = __uint_as_float((unsigned int)(sorted[ix] >> 16));
            outC[tid] = sCls[ix];
            float4 b = sBox[ix];
            outB[4*tid]=b.x; outB[4*tid+1]=b.y; outB[4*tid+2]=b.z; outB[4*tid+3]=b.w;
            accB[tid] = b; accA[tid] = sA[ix];
        } else {
            outS[tid] = -1.f; outC[tid] = -1.f;
            outB[4*tid]=-1.f; outB[4*tid+1]=-1.f; outB[4*tid+2]=-1.f; outB[4*tid+3]=-1.f;
        }
    }
    __syncthreads();
    if (!shFB) return;

    // ---- exact slow fallback: top-256 exhausted (never on real data) ----
    unsigned long long* red = supMask;
    while (true) {
        unsigned long long lk = lastK, best = 0;
        for (int i = tid; i < NPOS; i += 256) {
            unsigned long long k = mkkey(gs[i], i);
            if (k < lk && k > best) best = k;
        }
        red[tid] = best;
        __syncthreads();
        if (tid == 0) {
            unsigned long long b = 0;
            for (int j = 0; j < 256; ++j) if (red[j] > b) b = red[j];
            red[0] = b;
        }
        __syncthreads();
        best = red[0];
        __syncthreads();
        if (best == 0ull) break;
        float sc = __uint_as_float((unsigned int)(best >> 16));
        if (!(sc > MINS)) break;
        int p = 65535 - (int)(best & 0xFFFF);
        int lvl = p < 16384 ? 0 : p < 20480 ? 1 : p < 21504 ? 2 : p < 21760 ? 3 : 4;
        bool elig = true;
        if (lvl < 3) {                   // union membership: level-rank < 1000
            int base = lvl == 0 ? 0 : (lvl == 1 ? 16384 : 20480);
            int Nl   = lvl == 0 ? 16384 : (lvl == 1 ? 4096 : 1024);
            if (tid == 0) cntR = 0;
            __syncthreads();
            int c = 0;
            for (int q = tid; q < Nl; q += 256)
                if (mkkey(gs[base+q], base+q) > best) ++c;
            atomicAdd(&cntR, c);
            __syncthreads();
            elig = (cntR < 1000);
        }
        if (elig) {
            float4 nb = decode_box(P, img, p);
            float nA = (nb.z - nb.x)*(nb.w - nb.y);
            if (tid == 0) supFlag = 0;
            __syncthreads();
            if (tid < shNa) {
                float4 ab = accB[tid];
                float iw = fmaxf(fminf(nb.z,ab.z)-fmaxf(nb.x,ab.x),0.f);
                float ih = fmaxf(fminf(nb.w,ab.w)-fmaxf(nb.y,ab.y),0.f);
                float in_ = iw*ih;
                if (in_/(nA + accA[tid] - in_ + 1e-12f) > 0.6f) atomicOr(&supFlag, 1);
            }
            __syncthreads();
            if (!supFlag) {
                if (tid == 0) {
                    int k2 = shNa;
                    outS[k2] = sc; outC[k2] = (float)gCls[p];
                    outB[4*k2]=nb.x; outB[4*k2+1]=nb.y; outB[4*k2+2]=nb.z; outB[4*k2+3]=nb.w;
                    accB[k2] = nb; accA[k2] = nA; shNa = k2 + 1;
                }
                __syncthreads();
                if (shNa >= 100) break;
            }
        }
        if (tid == 0) lastK = best;
        __syncthreads();
    }
}

extern "C" void kernel_launch(void* const* d_in, const int* in_sizes, int n_in,
                              void* d_out, int out_size, void* d_ws, size_t ws_size,
                              hipStream_t stream) {
    Ptrs P;
    bool interleaved = (in_sizes[1] == 8 * 128 * 128 * 4);
    for (int i = 0; i < 5; ++i) {
        if (interleaved) {
            P.cls[i] = (const float*)d_in[3*i];
            P.reg[i] = (const float*)d_in[3*i + 1];
            P.ctr[i] = (const float*)d_in[3*i + 2];
        } else {
            P.cls[i] = (const float*)d_in[i];
            P.reg[i] = (const float*)d_in[5 + i];
            P.ctr[i] = (const float*)d_in[10 + i];
        }
    }

    char* wbase = (char*)d_ws;
    size_t off = 0;
    auto alloc = [&](size_t bytes) -> void* {
        void* r = wbase + off;
        off += (bytes + 255) & ~(size_t)255;
        return r;
    };
    float* scoreAll = (float*)alloc((size_t)8 * NPOS * 4);
    int*   clsAll   = (int*)alloc((size_t)8 * NPOS * 4);

    dim3 gA(341, 8);   // 341*64 = 21824 positions, level boundaries block-aligned
    k_score<<<gA, 256, 0, stream>>>(P, scoreAll, clsAll);
    k_nms6 <<<8,  256, 0, stream>>>(P, scoreAll, clsAll, (float*)d_out);
}